// Round 1
// baseline (226.304 us; speedup 1.0000x reference)
//
#include <hip/hip_runtime.h>
#include <cstdint>
#include <cstddef>

// Problem constants (from reference): T=1024 tokens, H=2048, F=1024, E=8, K=2
#define T_TOK 1024
#define H_DIM 2048
#define F_DIM 1024
#define E_EXP 8
#define BM 64
#define BN 64
#define BK 64
#define MAX_TILES 40   // sum_e ceil(cnt_e/64) <= 2048/64 + 8 = 40
#define ROWCAP 2560    // 40 tiles * 64 rows

// ---- workspace layout ----
// int-indexed control region (zeroed via hipMemsetAsync of first 512 B):
#define I_COUNTS 0      // int[8]
#define I_CURSOR 8      // int[8]
#define I_OFFS   16     // int[9]  padded prefix offsets
#define I_NTILES 25     // int
#define I_TILE_E 32     // int[48]
#define I_TILE_R0 80    // int[48]
#define I_TOPKID 128    // int[2048]
#define I_TOPKW  2176   // float[2048] (aliased region)
#define I_ROWTOK 4224   // int[2560]
#define I_ROWW   6784   // float[2560]
#define B_XB     37888                       // bf16 x [1024][2048]  (4 MB)
#define B_AWS    (37888 + T_TOK*H_DIM*2)     // bf16 act [2560][1024] (5 MB)
// total ws need ~9.1 MB

typedef __bf16 bf16x8 __attribute__((ext_vector_type(8)));
typedef float  f32x4  __attribute__((ext_vector_type(4)));

#define MFMA(a,b,c) __builtin_amdgcn_mfma_f32_16x16x32_bf16(a,b,c,0,0,0)

// ---------------- router: softmax top-2 + renormalize ----------------
// topk of softmax == topk of logits; renormalized weights:
// w0 = p0/(p0+p1) = 1/(1+exp(l1-l0)), w1 = 1-w0.
__global__ __launch_bounds__(256) void k_router(const float* __restrict__ logits,
                                                int* __restrict__ ws_i) {
  int t = blockIdx.x * 256 + threadIdx.x;
  if (t >= T_TOK) return;
  float l[E_EXP];
#pragma unroll
  for (int e = 0; e < E_EXP; ++e) l[e] = logits[t * E_EXP + e];
  int b0 = 0; float v0 = l[0];
#pragma unroll
  for (int e = 1; e < E_EXP; ++e) if (l[e] > v0) { v0 = l[e]; b0 = e; }
  int b1 = -1; float v1 = -3.4e38f;
#pragma unroll
  for (int e = 0; e < E_EXP; ++e) if (e != b0 && l[e] > v1) { v1 = l[e]; b1 = e; }
  float w0 = 1.f / (1.f + __expf(v1 - v0));
  float w1 = 1.f - w0;
  ws_i[I_TOPKID + t * 2 + 0] = b0;
  ws_i[I_TOPKID + t * 2 + 1] = b1;
  float* ws_f = (float*)ws_i;
  ws_f[I_TOPKW + t * 2 + 0] = w0;
  ws_f[I_TOPKW + t * 2 + 1] = w1;
  atomicAdd(&ws_i[I_COUNTS + b0], 1);
  atomicAdd(&ws_i[I_COUNTS + b1], 1);
}

// ---------------- scan: padded offsets + tile table + fill -1 ----------------
__global__ __launch_bounds__(256) void k_scan(int* __restrict__ ws_i) {
  if (threadIdx.x == 0) {
    int off = 0, nt = 0;
    for (int e = 0; e < E_EXP; ++e) {
      ws_i[I_OFFS + e] = off;
      int c = ws_i[I_COUNTS + e];
      int ntile = (c + BM - 1) / BM;
      for (int i = 0; i < ntile; ++i) {
        ws_i[I_TILE_E + nt] = e;
        ws_i[I_TILE_R0 + nt] = off + i * BM;
        ++nt;
      }
      off += ntile * BM;
      ws_i[I_CURSOR + e] = 0;
    }
    ws_i[I_OFFS + 8] = off;
    ws_i[I_NTILES] = nt;
  }
  __syncthreads();
  for (int i = threadIdx.x; i < ROWCAP; i += 256) ws_i[I_ROWTOK + i] = -1;
}

// ---------------- assign: scatter tokens into expert-sorted rows ----------------
__global__ __launch_bounds__(256) void k_assign(int* __restrict__ ws_i) {
  int t = blockIdx.x * 256 + threadIdx.x;
  if (t >= T_TOK) return;
  float* ws_f = (float*)ws_i;
#pragma unroll
  for (int k = 0; k < 2; ++k) {
    int e = ws_i[I_TOPKID + t * 2 + k];
    int p = atomicAdd(&ws_i[I_CURSOR + e], 1);
    int s = ws_i[I_OFFS + e] + p;
    ws_i[I_ROWTOK + s] = t;
    ws_f[I_ROWW + s] = ws_f[I_TOPKW + t * 2 + k];
  }
}

// ---------------- x fp32 -> bf16 once (4 MB, L2/L3-resident afterwards) ----------------
__global__ __launch_bounds__(256) void k_cvt(const float* __restrict__ x,
                                             __bf16* __restrict__ xb) {
  long i = (long)(blockIdx.x * 256 + threadIdx.x) * 8;
  float4 a = *(const float4*)(x + i);
  float4 b = *(const float4*)(x + i + 4);
  bf16x8 v;
  v[0] = (__bf16)a.x; v[1] = (__bf16)a.y; v[2] = (__bf16)a.z; v[3] = (__bf16)a.w;
  v[4] = (__bf16)b.x; v[5] = (__bf16)b.y; v[6] = (__bf16)b.z; v[7] = (__bf16)b.w;
  *(bf16x8*)(xb + i) = v;
}

// ---------------- GEMM1: a = silu(x·w1) * (x·w3), per expert row-tile ----------------
__global__ __launch_bounds__(256) void k_gemm1(const __bf16* __restrict__ xb,
                                               const float* __restrict__ w1,
                                               const float* __restrict__ w3,
                                               const int* __restrict__ ws_i,
                                               __bf16* __restrict__ aws) {
  __shared__ __bf16 As[BM][BK + 8];     // [row][k]
  __shared__ __bf16 B1s[BN][BK + 8];    // [n][k] (transposed for contiguous frag reads)
  __shared__ __bf16 B3s[BN][BK + 8];
  __shared__ int s_tok[BM];
  if ((int)blockIdx.x >= ws_i[I_NTILES]) return;
  const int e  = ws_i[I_TILE_E + blockIdx.x];
  const int r0 = ws_i[I_TILE_R0 + blockIdx.x];
  const int n0 = blockIdx.y * BN;
  const int tid = threadIdx.x, lane = tid & 63, wid = tid >> 6;
  const int wm = wid >> 1, wn = wid & 1;
  if (tid < BM) {
    int tk = ws_i[I_ROWTOK + r0 + tid];
    s_tok[tid] = tk < 0 ? 0 : tk;   // padded rows compute garbage, never scattered
  }
  __syncthreads();
  f32x4 accg[2][2] = {}; f32x4 accu[2][2] = {};
  const float* w1e = w1 + (size_t)e * H_DIM * F_DIM + n0;
  const float* w3e = w3 + (size_t)e * H_DIM * F_DIM + n0;
  const int l15 = lane & 15, lk = (lane >> 4) << 3;
  for (int k0 = 0; k0 < H_DIM; k0 += BK) {
#pragma unroll
    for (int it = 0; it < 2; ++it) {       // stage A: 64x64 bf16
      int idx = it * 2048 + tid * 8;
      int r = idx >> 6, c = idx & 63;
      *(bf16x8*)&As[r][c] = *(const bf16x8*)(xb + (size_t)s_tok[r] * H_DIM + (k0 + c));
    }
#pragma unroll
    for (int it = 0; it < 4; ++it) {       // stage B1/B3: fp32->bf16, transpose to [n][k]
      int idx = it * 1024 + tid * 4;
      int k = idx >> 6, n = idx & 63;
      float4 f1v = *(const float4*)(w1e + (size_t)(k0 + k) * F_DIM + n);
      float4 f3v = *(const float4*)(w3e + (size_t)(k0 + k) * F_DIM + n);
      B1s[n + 0][k] = (__bf16)f1v.x; B1s[n + 1][k] = (__bf16)f1v.y;
      B1s[n + 2][k] = (__bf16)f1v.z; B1s[n + 3][k] = (__bf16)f1v.w;
      B3s[n + 0][k] = (__bf16)f3v.x; B3s[n + 1][k] = (__bf16)f3v.y;
      B3s[n + 2][k] = (__bf16)f3v.z; B3s[n + 3][k] = (__bf16)f3v.w;
    }
    __syncthreads();
#pragma unroll
    for (int kk = 0; kk < 2; ++kk) {
      int kb = kk * 32 + lk;
      bf16x8 a0  = *(const bf16x8*)&As[wm * 32 + l15][kb];
      bf16x8 a1  = *(const bf16x8*)&As[wm * 32 + 16 + l15][kb];
      bf16x8 b10 = *(const bf16x8*)&B1s[wn * 32 + l15][kb];
      bf16x8 b11 = *(const bf16x8*)&B1s[wn * 32 + 16 + l15][kb];
      bf16x8 b30 = *(const bf16x8*)&B3s[wn * 32 + l15][kb];
      bf16x8 b31 = *(const bf16x8*)&B3s[wn * 32 + 16 + l15][kb];
      accg[0][0] = MFMA(a0, b10, accg[0][0]);
      accg[0][1] = MFMA(a0, b11, accg[0][1]);
      accg[1][0] = MFMA(a1, b10, accg[1][0]);
      accg[1][1] = MFMA(a1, b11, accg[1][1]);
      accu[0][0] = MFMA(a0, b30, accu[0][0]);
      accu[0][1] = MFMA(a0, b31, accu[0][1]);
      accu[1][0] = MFMA(a1, b30, accu[1][0]);
      accu[1][1] = MFMA(a1, b31, accu[1][1]);
    }
    __syncthreads();
  }
  // epilogue: silu(g)*u -> bf16 activations (C layout: col=lane&15, row=(lane>>4)*4+reg)
#pragma unroll
  for (int fm = 0; fm < 2; ++fm)
#pragma unroll
    for (int fn = 0; fn < 2; ++fn)
#pragma unroll
      for (int r = 0; r < 4; ++r) {
        float g = accg[fm][fn][r], u = accu[fm][fn][r];
        float a = g / (1.f + __expf(-g)) * u;
        int row = r0 + wm * 32 + fm * 16 + ((lane >> 4) << 2) + r;
        int col = n0 + wn * 32 + fn * 16 + l15;
        aws[(size_t)row * F_DIM + col] = (__bf16)a;
      }
}

// ---------------- GEMM2: y = a·w2, weighted scatter into out ----------------
__global__ __launch_bounds__(256) void k_gemm2(const __bf16* __restrict__ aws,
                                               const float* __restrict__ w2,
                                               const int* __restrict__ ws_i,
                                               float* __restrict__ out) {
  __shared__ __bf16 As[BM][BK + 8];
  __shared__ __bf16 Bs[BN][BK + 8];
  __shared__ int s_tok[BM];
  __shared__ float s_w[BM];
  if ((int)blockIdx.x >= ws_i[I_NTILES]) return;
  const int e  = ws_i[I_TILE_E + blockIdx.x];
  const int r0 = ws_i[I_TILE_R0 + blockIdx.x];
  const int h0 = blockIdx.y * BN;
  const int tid = threadIdx.x, lane = tid & 63, wid = tid >> 6;
  const int wm = wid >> 1, wn = wid & 1;
  const float* ws_f = (const float*)ws_i;
  if (tid < BM) {
    s_tok[tid] = ws_i[I_ROWTOK + r0 + tid];
    s_w[tid]   = ws_f[I_ROWW + r0 + tid];
  }
  __syncthreads();
  f32x4 acc[2][2] = {};
  const float* w2e = w2 + (size_t)e * F_DIM * H_DIM + h0;
  const int l15 = lane & 15, lk = (lane >> 4) << 3;
  for (int k0 = 0; k0 < F_DIM; k0 += BK) {
#pragma unroll
    for (int it = 0; it < 2; ++it) {
      int idx = it * 2048 + tid * 8;
      int r = idx >> 6, c = idx & 63;
      *(bf16x8*)&As[r][c] = *(const bf16x8*)(aws + (size_t)(r0 + r) * F_DIM + k0 + c);
    }
#pragma unroll
    for (int it = 0; it < 4; ++it) {
      int idx = it * 1024 + tid * 4;
      int k = idx >> 6, n = idx & 63;
      float4 f = *(const float4*)(w2e + (size_t)(k0 + k) * H_DIM + n);
      Bs[n + 0][k] = (__bf16)f.x; Bs[n + 1][k] = (__bf16)f.y;
      Bs[n + 2][k] = (__bf16)f.z; Bs[n + 3][k] = (__bf16)f.w;
    }
    __syncthreads();
#pragma unroll
    for (int kk = 0; kk < 2; ++kk) {
      int kb = kk * 32 + lk;
      bf16x8 a0 = *(const bf16x8*)&As[wm * 32 + l15][kb];
      bf16x8 a1 = *(const bf16x8*)&As[wm * 32 + 16 + l15][kb];
      bf16x8 b0 = *(const bf16x8*)&Bs[wn * 32 + l15][kb];
      bf16x8 b1 = *(const bf16x8*)&Bs[wn * 32 + 16 + l15][kb];
      acc[0][0] = MFMA(a0, b0, acc[0][0]);
      acc[0][1] = MFMA(a0, b1, acc[0][1]);
      acc[1][0] = MFMA(a1, b0, acc[1][0]);
      acc[1][1] = MFMA(a1, b1, acc[1][1]);
    }
    __syncthreads();
  }
  // weighted scatter; exactly 2 atomic adds per output element (K=2) -> deterministic
#pragma unroll
  for (int fm = 0; fm < 2; ++fm)
#pragma unroll
    for (int fn = 0; fn < 2; ++fn)
#pragma unroll
      for (int r = 0; r < 4; ++r) {
        int lrow = wm * 32 + fm * 16 + ((lane >> 4) << 2) + r;
        int t = s_tok[lrow];
        if (t >= 0) {
          float v = acc[fm][fn][r] * s_w[lrow];
          atomicAdd(out + (size_t)t * H_DIM + h0 + wn * 32 + fn * 16 + l15, v);
        }
      }
}

extern "C" void kernel_launch(void* const* d_in, const int* in_sizes, int n_in,
                              void* d_out, int out_size, void* d_ws, size_t ws_size,
                              hipStream_t stream) {
  (void)in_sizes; (void)n_in; (void)out_size; (void)ws_size;
  const float* x      = (const float*)d_in[0];
  const float* logits = (const float*)d_in[1];
  const float* w1     = (const float*)d_in[2];
  const float* w3     = (const float*)d_in[3];
  const float* w2     = (const float*)d_in[4];
  float* out = (float*)d_out;
  int* ws_i = (int*)d_ws;
  __bf16* xb  = (__bf16*)((char*)d_ws + B_XB);
  __bf16* aws = (__bf16*)((char*)d_ws + B_AWS);

  hipMemsetAsync(d_ws, 0, 512, stream);                                // counts/cursor/ctrl
  hipMemsetAsync(d_out, 0, (size_t)T_TOK * H_DIM * sizeof(float), stream);

  k_router<<<dim3(T_TOK / 256), 256, 0, stream>>>(logits, ws_i);
  k_scan<<<1, 256, 0, stream>>>(ws_i);
  k_assign<<<dim3(T_TOK / 256), 256, 0, stream>>>(ws_i);
  k_cvt<<<dim3(T_TOK * H_DIM / (256 * 8)), 256, 0, stream>>>(x, xb);
  k_gemm1<<<dim3(MAX_TILES, F_DIM / BN), 256, 0, stream>>>(xb, w1, w3, ws_i, aws);
  k_gemm2<<<dim3(MAX_TILES, H_DIM / BN), 256, 0, stream>>>(aws, w2, ws_i, out);
}

// Round 2
// 137.302 us; speedup vs baseline: 1.6482x; 1.6482x over previous
//
#include <hip/hip_runtime.h>
#include <cstdint>
#include <cstddef>

// T=1024 tokens, H=2048, F=1024, E=8, K=2
#define T_TOK 1024
#define H_DIM 2048
#define F_DIM 1024
#define E_EXP 8
#define BM 64
#define BN 64
#define BK 64
#define SP 70          // LDS row stride in bf16 elems (140 B: bank step 3, coprime 32)
#define MAX_TILES 40
#define ROWCAP 2560

// ---- workspace layout (ints unless noted) ----
#define I_COUNTS 0      // int[8]
#define I_CURSOR 8      // int[8]
#define I_OFFS   16     // int[9]
#define I_NTILES 25     // int
#define I_TILE_E 32     // int[48]
#define I_TILE_R0 80    // int[48]
#define I_TOPKID 128    // int[2048]
#define I_TOPKW  2176   // float[2048]
#define I_ROWTOK 4224   // int[2560]
#define I_ROWW   6784   // float[2560]
#define B_XB     37888                       // bf16 x [1024][2048]
#define B_AWS    (37888 + T_TOK*H_DIM*2)     // bf16 act [2560][1024]

typedef __bf16 bf16x8 __attribute__((ext_vector_type(8)));
typedef __bf16 bf16x4 __attribute__((ext_vector_type(4)));
typedef float  f32x4  __attribute__((ext_vector_type(4)));

#define MFMA(a,b,c) __builtin_amdgcn_mfma_f32_16x16x32_bf16(a,b,c,0,0,0)

// ---------------- router ----------------
__global__ __launch_bounds__(256) void k_router(const float* __restrict__ logits,
                                                int* __restrict__ ws_i) {
  int t = blockIdx.x * 256 + threadIdx.x;
  if (t >= T_TOK) return;
  float l[E_EXP];
#pragma unroll
  for (int e = 0; e < E_EXP; ++e) l[e] = logits[t * E_EXP + e];
  int b0 = 0; float v0 = l[0];
#pragma unroll
  for (int e = 1; e < E_EXP; ++e) if (l[e] > v0) { v0 = l[e]; b0 = e; }
  int b1 = -1; float v1 = -3.4e38f;
#pragma unroll
  for (int e = 0; e < E_EXP; ++e) if (e != b0 && l[e] > v1) { v1 = l[e]; b1 = e; }
  float w0 = 1.f / (1.f + __expf(v1 - v0));
  ws_i[I_TOPKID + t * 2 + 0] = b0;
  ws_i[I_TOPKID + t * 2 + 1] = b1;
  float* ws_f = (float*)ws_i;
  ws_f[I_TOPKW + t * 2 + 0] = w0;
  ws_f[I_TOPKW + t * 2 + 1] = 1.f - w0;
  atomicAdd(&ws_i[I_COUNTS + b0], 1);
  atomicAdd(&ws_i[I_COUNTS + b1], 1);
}

// ---------------- scan ----------------
__global__ __launch_bounds__(256) void k_scan(int* __restrict__ ws_i) {
  if (threadIdx.x == 0) {
    int off = 0, nt = 0;
    for (int e = 0; e < E_EXP; ++e) {
      ws_i[I_OFFS + e] = off;
      int c = ws_i[I_COUNTS + e];
      int ntile = (c + BM - 1) / BM;
      for (int i = 0; i < ntile; ++i) {
        ws_i[I_TILE_E + nt] = e;
        ws_i[I_TILE_R0 + nt] = off + i * BM;
        ++nt;
      }
      off += ntile * BM;
      ws_i[I_CURSOR + e] = 0;
    }
    ws_i[I_OFFS + 8] = off;
    ws_i[I_NTILES] = nt;
  }
  __syncthreads();
  for (int i = threadIdx.x; i < ROWCAP; i += 256) ws_i[I_ROWTOK + i] = -1;
}

// ---------------- assign ----------------
__global__ __launch_bounds__(256) void k_assign(int* __restrict__ ws_i) {
  int t = blockIdx.x * 256 + threadIdx.x;
  if (t >= T_TOK) return;
  float* ws_f = (float*)ws_i;
#pragma unroll
  for (int k = 0; k < 2; ++k) {
    int e = ws_i[I_TOPKID + t * 2 + k];
    int p = atomicAdd(&ws_i[I_CURSOR + e], 1);
    int s = ws_i[I_OFFS + e] + p;
    ws_i[I_ROWTOK + s] = t;
    ws_f[I_ROWW + s] = ws_f[I_TOPKW + t * 2 + k];
  }
}

// ---------------- x fp32 -> bf16 ----------------
__global__ __launch_bounds__(256) void k_cvt(const float* __restrict__ x,
                                             __bf16* __restrict__ xb) {
  long i = (long)(blockIdx.x * 256 + threadIdx.x) * 8;
  float4 a = *(const float4*)(x + i);
  float4 b = *(const float4*)(x + i + 4);
  bf16x8 v;
  v[0] = (__bf16)a.x; v[1] = (__bf16)a.y; v[2] = (__bf16)a.z; v[3] = (__bf16)a.w;
  v[4] = (__bf16)b.x; v[5] = (__bf16)b.y; v[6] = (__bf16)b.z; v[7] = (__bf16)b.w;
  *(bf16x8*)(xb + i) = v;
}

// ---------------- GEMM1: g/u = x·w1 / x·w3, silu-combine -> aws (bf16) ----------------
__global__ __launch_bounds__(256) void k_gemm1(const __bf16* __restrict__ xb,
                                               const float* __restrict__ w1,
                                               const float* __restrict__ w3,
                                               const int* __restrict__ ws_i,
                                               __bf16* __restrict__ aws) {
  __shared__ __bf16 As[BM][SP];
  __shared__ __bf16 B1s[BN][SP];
  __shared__ __bf16 B3s[BN][SP];
  __shared__ int s_tok[BM];
  // XCD-grouping swizzle: 640 = 8 XCD * 80; same-(e,n0) M-tiles adjacent per XCD
  const int p = blockIdx.x;
  const int lg = (p & 7) * 80 + (p >> 3);
  const int tile = lg % MAX_TILES;
  const int n0 = (lg / MAX_TILES) * BN;
  if (tile >= ws_i[I_NTILES]) return;
  const int e  = ws_i[I_TILE_E + tile];
  const int r0 = ws_i[I_TILE_R0 + tile];
  const int tid = threadIdx.x, lane = tid & 63, wid = tid >> 6;
  const int wm = wid >> 1, wn = wid & 1;
  const int l15 = lane & 15, lk8 = (lane >> 4) << 3;
  // staging coords
  const int ar = tid >> 3, ac = (tid & 7) * 8;      // A: 2 rows (ar, ar+32) x 8 cols
  const int nb = (tid & 15) * 4, kq = (tid >> 4) * 4; // B: 4n x 4k block
  if (tid < BM) {
    int tk = ws_i[I_ROWTOK + r0 + tid];
    s_tok[tid] = tk < 0 ? 0 : tk;
  }
  __syncthreads();
  const int tok0 = s_tok[ar], tok1 = s_tok[ar + 32];
  const __bf16* xA0 = xb + (size_t)tok0 * H_DIM + ac;
  const __bf16* xA1 = xb + (size_t)tok1 * H_DIM + ac;
  const float* pB1 = w1 + (size_t)e * H_DIM * F_DIM + n0 + nb + (size_t)kq * F_DIM;
  const float* pB3 = w3 + (size_t)e * H_DIM * F_DIM + n0 + nb + (size_t)kq * F_DIM;

  bf16x8 rA0, rA1;
  f32x4 q1[4], q3[4];

  auto LOADG = [&](int K0) {
    rA0 = *(const bf16x8*)(xA0 + K0);
    rA1 = *(const bf16x8*)(xA1 + K0);
#pragma unroll
    for (int j = 0; j < 4; ++j) {
      q1[j] = *(const f32x4*)(pB1 + (size_t)(K0 + j) * F_DIM);
      q3[j] = *(const f32x4*)(pB3 + (size_t)(K0 + j) * F_DIM);
    }
  };
  auto WRITEL = [&]() {
    *(bf16x8*)&As[ar][ac] = rA0;
    *(bf16x8*)&As[ar + 32][ac] = rA1;
#pragma unroll
    for (int u = 0; u < 4; ++u) {
      bf16x4 v1, v3;
#pragma unroll
      for (int j = 0; j < 4; ++j) { v1[j] = (__bf16)q1[j][u]; v3[j] = (__bf16)q3[j][u]; }
      *(bf16x4*)&B1s[nb + u][kq] = v1;
      *(bf16x4*)&B3s[nb + u][kq] = v3;
    }
  };

  f32x4 accg[2][2] = {}; f32x4 accu[2][2] = {};
  LOADG(0);
  for (int k0 = 0; k0 < H_DIM; k0 += BK) {
    if (k0) __syncthreads();          // prev compute done reading LDS
    WRITEL();                          // regs (tile k0) -> LDS
    if (k0 + BK < H_DIM) LOADG(k0 + BK); // issue next tile's loads, fly during MFMA
    __syncthreads();
#pragma unroll
    for (int kk = 0; kk < 2; ++kk) {
      const int kb = kk * 32 + lk8;
      bf16x8 a0  = *(const bf16x8*)&As[wm * 32 + l15][kb];
      bf16x8 a1  = *(const bf16x8*)&As[wm * 32 + 16 + l15][kb];
      bf16x8 b10 = *(const bf16x8*)&B1s[wn * 32 + l15][kb];
      bf16x8 b11 = *(const bf16x8*)&B1s[wn * 32 + 16 + l15][kb];
      bf16x8 b30 = *(const bf16x8*)&B3s[wn * 32 + l15][kb];
      bf16x8 b31 = *(const bf16x8*)&B3s[wn * 32 + 16 + l15][kb];
      accg[0][0] = MFMA(a0, b10, accg[0][0]);
      accg[0][1] = MFMA(a0, b11, accg[0][1]);
      accg[1][0] = MFMA(a1, b10, accg[1][0]);
      accg[1][1] = MFMA(a1, b11, accg[1][1]);
      accu[0][0] = MFMA(a0, b30, accu[0][0]);
      accu[0][1] = MFMA(a0, b31, accu[0][1]);
      accu[1][0] = MFMA(a1, b30, accu[1][0]);
      accu[1][1] = MFMA(a1, b31, accu[1][1]);
    }
  }
  // epilogue: silu(g)*u -> bf16 (C layout: col=lane&15, row=(lane>>4)*4+reg)
#pragma unroll
  for (int fm = 0; fm < 2; ++fm)
#pragma unroll
    for (int fn = 0; fn < 2; ++fn)
#pragma unroll
      for (int r = 0; r < 4; ++r) {
        float g = accg[fm][fn][r], u = accu[fm][fn][r];
        float a = g / (1.f + __expf(-g)) * u;
        int row = r0 + wm * 32 + fm * 16 + ((lane >> 4) << 2) + r;
        int col = n0 + wn * 32 + fn * 16 + l15;
        aws[(size_t)row * F_DIM + col] = (__bf16)a;
      }
}

// ---------------- GEMM2: y = a·w2, weighted atomic scatter ----------------
__global__ __launch_bounds__(256) void k_gemm2(const __bf16* __restrict__ aws,
                                               const float* __restrict__ w2,
                                               const int* __restrict__ ws_i,
                                               float* __restrict__ out) {
  __shared__ __bf16 As[BM][SP];
  __shared__ __bf16 Bs[BN][SP];
  __shared__ int s_tok[BM];
  __shared__ float s_w[BM];
  const int p = blockIdx.x;                 // 1280 = 8 XCD * 160
  const int lg = (p & 7) * 160 + (p >> 3);
  const int tile = lg % MAX_TILES;
  const int h0 = (lg / MAX_TILES) * BN;
  if (tile >= ws_i[I_NTILES]) return;
  const int e  = ws_i[I_TILE_E + tile];
  const int r0 = ws_i[I_TILE_R0 + tile];
  const int tid = threadIdx.x, lane = tid & 63, wid = tid >> 6;
  const int wm = wid >> 1, wn = wid & 1;
  const int l15 = lane & 15, lk8 = (lane >> 4) << 3;
  const int ar = tid >> 3, ac = (tid & 7) * 8;
  const int nb = (tid & 15) * 4, kq = (tid >> 4) * 4;
  const float* ws_f = (const float*)ws_i;
  if (tid < BM) {
    s_tok[tid] = ws_i[I_ROWTOK + r0 + tid];
    s_w[tid]   = ws_f[I_ROWW + r0 + tid];
  }
  __syncthreads();
  const __bf16* pA0 = aws + (size_t)(r0 + ar) * F_DIM + ac;
  const __bf16* pA1 = aws + (size_t)(r0 + ar + 32) * F_DIM + ac;
  const float* pB2 = w2 + (size_t)e * F_DIM * H_DIM + h0 + nb + (size_t)kq * H_DIM;

  bf16x8 rA0, rA1;
  f32x4 q2[4];
  auto LOADG = [&](int K0) {
    rA0 = *(const bf16x8*)(pA0 + K0);
    rA1 = *(const bf16x8*)(pA1 + K0);
#pragma unroll
    for (int j = 0; j < 4; ++j) q2[j] = *(const f32x4*)(pB2 + (size_t)(K0 + j) * H_DIM);
  };
  auto WRITEL = [&]() {
    *(bf16x8*)&As[ar][ac] = rA0;
    *(bf16x8*)&As[ar + 32][ac] = rA1;
#pragma unroll
    for (int u = 0; u < 4; ++u) {
      bf16x4 v;
#pragma unroll
      for (int j = 0; j < 4; ++j) v[j] = (__bf16)q2[j][u];
      *(bf16x4*)&Bs[nb + u][kq] = v;
    }
  };

  f32x4 acc[2][2] = {};
  LOADG(0);
  for (int k0 = 0; k0 < F_DIM; k0 += BK) {
    if (k0) __syncthreads();
    WRITEL();
    if (k0 + BK < F_DIM) LOADG(k0 + BK);
    __syncthreads();
#pragma unroll
    for (int kk = 0; kk < 2; ++kk) {
      const int kb = kk * 32 + lk8;
      bf16x8 a0 = *(const bf16x8*)&As[wm * 32 + l15][kb];
      bf16x8 a1 = *(const bf16x8*)&As[wm * 32 + 16 + l15][kb];
      bf16x8 b0 = *(const bf16x8*)&Bs[wn * 32 + l15][kb];
      bf16x8 b1 = *(const bf16x8*)&Bs[wn * 32 + 16 + l15][kb];
      acc[0][0] = MFMA(a0, b0, acc[0][0]);
      acc[0][1] = MFMA(a0, b1, acc[0][1]);
      acc[1][0] = MFMA(a1, b0, acc[1][0]);
      acc[1][1] = MFMA(a1, b1, acc[1][1]);
    }
  }
#pragma unroll
  for (int fm = 0; fm < 2; ++fm)
#pragma unroll
    for (int fn = 0; fn < 2; ++fn)
#pragma unroll
      for (int r = 0; r < 4; ++r) {
        int lrow = wm * 32 + fm * 16 + ((lane >> 4) << 2) + r;
        int t = s_tok[lrow];
        if (t >= 0) {
          float v = acc[fm][fn][r] * s_w[lrow];
          atomicAdd(out + (size_t)t * H_DIM + h0 + wn * 32 + fn * 16 + l15, v);
        }
      }
}

extern "C" void kernel_launch(void* const* d_in, const int* in_sizes, int n_in,
                              void* d_out, int out_size, void* d_ws, size_t ws_size,
                              hipStream_t stream) {
  (void)in_sizes; (void)n_in; (void)out_size; (void)ws_size;
  const float* x      = (const float*)d_in[0];
  const float* logits = (const float*)d_in[1];
  const float* w1     = (const float*)d_in[2];
  const float* w3     = (const float*)d_in[3];
  const float* w2     = (const float*)d_in[4];
  float* out = (float*)d_out;
  int* ws_i = (int*)d_ws;
  __bf16* xb  = (__bf16*)((char*)d_ws + B_XB);
  __bf16* aws = (__bf16*)((char*)d_ws + B_AWS);

  hipMemsetAsync(d_ws, 0, 512, stream);
  hipMemsetAsync(d_out, 0, (size_t)T_TOK * H_DIM * sizeof(float), stream);

  k_router<<<dim3(T_TOK / 256), 256, 0, stream>>>(logits, ws_i);
  k_scan<<<1, 256, 0, stream>>>(ws_i);
  k_assign<<<dim3(T_TOK / 256), 256, 0, stream>>>(ws_i);
  k_cvt<<<dim3(T_TOK * H_DIM / (256 * 8)), 256, 0, stream>>>(x, xb);
  k_gemm1<<<dim3(MAX_TILES * (F_DIM / BN)), 256, 0, stream>>>(xb, w1, w3, ws_i, aws);
  k_gemm2<<<dim3(MAX_TILES * (H_DIM / BN)), 256, 0, stream>>>(aws, w2, ws_i, out);
}